// Round 5
// baseline (342.128 us; speedup 1.0000x reference)
//
#include <hip/hip_runtime.h>
#include <math.h>

#define B 16
#define C 2
#define T 2000
#define F 257

#define RES_SIZE   (B * C * T * F * 2)   // 32,896,000
#define OFF_SFINAL (RES_SIZE)            // + B*F
#define OFF_SMOOTH (RES_SIZE + B * F)    // + B*T*F

// ---- ch0 block-local scan geometry ----
#define FW 16                 // f-columns per block
#define TC 16                 // chunks per block (thread c-dim)
#define LW (T / TC)           // 125 timesteps per chunk
#define NFT ((F + FW - 1) / FW)   // 17 f-tiles
#define NCH0 (B * NFT)            // 272 ch0 blocks

// ---- ch1 elementwise geometry ----
#define SLAB4   (T * F * 2 / 4)            // 257,000 float4 per (b, ch1) slab
#define N_V4    (B * SLAB4)                // 4,112,000 float4 threads
#define G1      ((N_V4 + 255) / 256)       // 16,063 blocks

__device__ __forceinline__ float sigmoidf_(float x) {
    return 1.0f / (1.0f + expf(-x));
}

// ONE kernel, no cross-block dependencies.
// Blocks [0, NCH0): ch0. Each block owns (b, 16-f tile, ALL T):
//   phase A: thread (c,f) scans its 125-step chunk with s=0 -> carry in LDS
//   (one __syncthreads)
//   phase B: intra-block fold of carries -> exact chunk-start state
//   phase C: re-walk the chunk (input is L3-hot, read ~us ago), emit
//            res ch0 + smooth; c==TC-1 threads emit s_final (pre-sqrt).
// Blocks [NCH0, NCH0+G1): ch1 pure elementwise, float4-vectorized.
// ch0 blocks are FIRST so their latency-bound chains start immediately and
// the 16k ch1 streaming blocks backfill the machine around them.
__global__ __launch_bounds__(256) void k_all(const float* __restrict__ input,
                                             const float* __restrict__ s_1,
                                             const float* __restrict__ alpha_param,
                                             const float* __restrict__ weights,
                                             const float* __restrict__ bias,
                                             float* __restrict__ out) {
    int bid = blockIdx.x;
    if (bid < NCH0) {
        // ---------------- channel 0 ----------------
        int ft = bid % NFT;
        int b  = bid / NFT;
        int tid = threadIdx.x;
        int f = tid & (FW - 1);
        int c = tid >> 4;
        int fg = ft * FW + f;
        bool act = (fg < F);

        __shared__ float carr[TC][FW + 1];   // +1 pad (broadcast reads anyway)

        float a = 0.0f, beta = 1.0f, s = 0.0f;
        const float2* base = (const float2*)input;   // dummy init
        if (act) {
            a = sigmoidf_(alpha_param[fg]);
            beta = 1.0f - a;
            base = (const float2*)input
                 + ((size_t)(b * C + 0) * T + (size_t)c * LW) * F + fg;
#pragma unroll 5
            for (int t = 0; t < LW; ++t) {
                float2 v = base[(size_t)t * F];
                s = beta * s + a * (v.x * v.x + v.y * v.y);
            }
        }
        carr[c][f] = s;
        __syncthreads();
        if (!act) return;

        // bL = beta^LW (once per thread; 125 mults, negligible)
        float bL = 1.0f;
        for (int i = 0; i < LW; ++i) bL *= beta;

        // chunk-start state: fold c carries (LDS broadcast reads, <=15 iters)
        float S = s_1[b * F + fg];
        for (int j = 0; j < c; ++j) S = fmaf(bL, S, carr[j][f]);

        float w0 = weights[fg];   // channel 0 slice
        float q0 = bias[fg];

        float2* res = (float2*)out
                    + ((size_t)(b * C + 0) * T + (size_t)c * LW) * F + fg;
        float* smb = out + OFF_SMOOTH + ((size_t)b * T + (size_t)c * LW) * F + fg;

        s = S;
#pragma unroll 5
        for (int t = 0; t < LW; ++t) {
            float2 v = base[(size_t)t * F];      // L3-hot re-read
            s = beta * s + a * (v.x * v.x + v.y * v.y);
            float sm = sqrtf(s);
            float inv = 1.0f / (sm + 1e-8f);
            float2 rr;
            rr.x = v.x * inv * w0 + q0;
            rr.y = v.y * inv * w0 + q0;
            res[(size_t)t * F] = rr;
            smb[(size_t)t * F] = sm;
        }
        if (c == TC - 1) out[OFF_SFINAL + (size_t)b * F + fg] = s;  // pre-sqrt
    } else {
        // ---------------- channel 1: elementwise, float4 ----------------
        int idx = (bid - NCH0) * 256 + threadIdx.x;
        if (idx >= N_V4) return;
        int b   = idx / SLAB4;
        int rem = idx - b * SLAB4;

        const float4* ip = (const float4*)(input + ((size_t)(b * C + 1) * T) * F * 2) + rem;
        float4 v = *ip;

        int e  = rem * 2;              // float2 index within slab
        int f0 = e % F;                // magic-mul, F=257 constant
        int f1 = (f0 + 1 == F) ? 0 : (f0 + 1);

        float w0 = weights[F + f0], w1 = weights[F + f1];
        float q0 = bias[F + f0],    q1 = bias[F + f1];

        float inv0 = 1.0f / (sqrtf(v.x * v.x + v.y * v.y) + 1e-8f);
        float inv1 = 1.0f / (sqrtf(v.z * v.z + v.w * v.w) + 1e-8f);

        float4 rr;
        rr.x = v.x * inv0 * w0 + q0;
        rr.y = v.y * inv0 * w0 + q0;
        rr.z = v.z * inv1 * w1 + q1;
        rr.w = v.w * inv1 * w1 + q1;

        float4* rp = (float4*)(out + ((size_t)(b * C + 1) * T) * F * 2) + rem;
        *rp = rr;
    }
}

extern "C" void kernel_launch(void* const* d_in, const int* in_sizes, int n_in,
                              void* d_out, int out_size, void* d_ws, size_t ws_size,
                              hipStream_t stream) {
    const float* input       = (const float*)d_in[0];
    const float* s_1         = (const float*)d_in[1];
    const float* weights     = (const float*)d_in[2];
    const float* bias        = (const float*)d_in[3];
    const float* alpha_param = (const float*)d_in[4];
    float* out = (float*)d_out;

    k_all<<<NCH0 + G1, 256, 0, stream>>>(input, s_1, alpha_param, weights, bias, out);
}

// Round 6
// 288.998 us; speedup vs baseline: 1.1838x; 1.1838x over previous
//
#include <hip/hip_runtime.h>
#include <math.h>

#define B 16
#define C 2
#define T 2000
#define F 257
#define NC 100           // chunks per (b,f)
#define L  (T / NC)      // 20 timesteps per chunk

#define RES_SIZE   (B * C * T * F * 2)   // 32,896,000
#define OFF_SFINAL (RES_SIZE)            // + B*F
#define OFF_SMOOTH (RES_SIZE + B * F)    // + B*T*F

#define N_CARRY (B * NC * F)             // 411,200 threads (carries / phase-2)
#define G0      ((N_CARRY + 255) / 256)  // 1607 blocks
#define SLAB4   (T * F * 2 / 4)          // 257,000 float4 per (b, ch1) slab
#define N_V4    (B * SLAB4)              // 4,112,000 float4 threads for ch1
#define G1      ((N_V4 + 255) / 256)     // 16,063 blocks

typedef float f32x2 __attribute__((ext_vector_type(2)));
typedef float f32x4 __attribute__((ext_vector_type(4)));

__device__ __forceinline__ float sigmoidf_(float x) {
    return 1.0f / (1.0f + expf(-x));
}

// Phase 1 (fused): blocks [0,G1) do the channel-1 elementwise path (float4,
// NON-TEMPORAL loads+stores: ch1 data is touched exactly once, so keep it
// out of L3 and reserve L3 for the ch0 input that phase 2 re-reads).
// Blocks [G1, G1+G0) compute ch0 per-chunk carries (normal/cached loads —
// these SHOULD populate L3 for phase 2). Carries run last so ch0 is
// freshest in L3 when phase 2 starts.
__global__ __launch_bounds__(256) void k_phase1(const float* __restrict__ input,
                                                const float* __restrict__ alpha_param,
                                                const float* __restrict__ weights,
                                                const float* __restrict__ bias,
                                                float* __restrict__ carry,
                                                float* __restrict__ out) {
    int bid = blockIdx.x;
    if (bid < G1) {
        // ---- channel 1: pure elementwise, float4, streaming cache policy ----
        int idx = bid * 256 + threadIdx.x;
        if (idx >= N_V4) return;
        int b   = idx / SLAB4;
        int rem = idx - b * SLAB4;

        const f32x4* ip = (const f32x4*)(input + ((size_t)(b * C + 1) * T) * F * 2) + rem;
        f32x4 v = __builtin_nontemporal_load(ip);

        int e  = rem * 2;              // float2 index within slab
        int f0 = e % F;                // magic-mul, F=257 constant
        int f1 = (f0 + 1 == F) ? 0 : (f0 + 1);

        float w0 = weights[F + f0], w1 = weights[F + f1];
        float q0 = bias[F + f0],    q1 = bias[F + f1];

        float inv0 = 1.0f / (sqrtf(v.x * v.x + v.y * v.y) + 1e-8f);
        float inv1 = 1.0f / (sqrtf(v.z * v.z + v.w * v.w) + 1e-8f);

        f32x4 rr;
        rr.x = v.x * inv0 * w0 + q0;
        rr.y = v.y * inv0 * w0 + q0;
        rr.z = v.z * inv1 * w1 + q1;
        rr.w = v.w * inv1 * w1 + q1;

        f32x4* rp = (f32x4*)(out + ((size_t)(b * C + 1) * T) * F * 2) + rem;
        __builtin_nontemporal_store(rr, rp);
    } else {
        // ---- chunk carries: recurrence with s=0 over L steps (cached reads) ----
        int tid = (bid - G1) * 256 + threadIdx.x;
        if (tid >= N_CARRY) return;
        int f = tid % F;
        int r = tid / F;
        int c = r % NC;
        int b = r / NC;

        float a = sigmoidf_(alpha_param[f]);
        float beta = 1.0f - a;

        const float2* inp = (const float2*)input
                          + ((size_t)(b * C + 0) * T + (size_t)c * L) * F + f;
        float s = 0.0f;
#pragma unroll
        for (int t = 0; t < L; ++t) {
            float2 v = inp[(size_t)t * F];
            s = beta * s + a * (v.x * v.x + v.y * v.y);
        }
        carry[((size_t)b * NC + c) * F + f] = s;
    }
}

// Phase 2 (fused scan + final): each (b,c,f) thread folds its own chunk-start
// state from the L2-resident carry buffer, runs the exact per-step recurrence
// (ch0 input should now be L3-hot), writes res ch0 + smooth with
// NON-TEMPORAL stores (outputs are never re-read); c==NC-1 emits s_final.
__global__ __launch_bounds__(256) void k_phase2(const float* __restrict__ input,
                                                const float* __restrict__ s_1,
                                                const float* __restrict__ alpha_param,
                                                const float* __restrict__ weights,
                                                const float* __restrict__ bias,
                                                const float* __restrict__ carry,
                                                float* __restrict__ out) {
    int tid = blockIdx.x * 256 + threadIdx.x;
    if (tid >= N_CARRY) return;
    int f = tid % F;
    int r = tid / F;
    int c = r % NC;
    int b = r / NC;

    float a = sigmoidf_(alpha_param[f]);
    float beta = 1.0f - a;
    float bL = 1.0f;
#pragma unroll
    for (int i = 0; i < L; ++i) bL *= beta;
    float bL2 = bL * bL;
    float bL3 = bL2 * bL;
    float bL4 = bL2 * bL2;

    // redundant per-thread prefix over carries (L2-resident, 1.6 MB buffer);
    // 4-way unrolled: 4 independent loads per iteration, short dep chain
    const float* cp = carry + (size_t)b * NC * F + f;
    float s = s_1[b * F + f];
    int j = 0;
    for (; j + 4 <= c; j += 4) {
        float c0 = cp[(size_t)(j    ) * F];
        float c1 = cp[(size_t)(j + 1) * F];
        float c2 = cp[(size_t)(j + 2) * F];
        float c3 = cp[(size_t)(j + 3) * F];
        s = fmaf(bL4, s, fmaf(bL3, c0, fmaf(bL2, c1, fmaf(bL, c2, c3))));
    }
    for (; j < c; ++j) s = fmaf(bL, s, cp[(size_t)j * F]);

    float w0 = weights[f];   // channel 0
    float q0 = bias[f];

    const float2* inp = (const float2*)input
                      + ((size_t)(b * C + 0) * T + (size_t)c * L) * F + f;
    f32x2* res = (f32x2*)out
               + ((size_t)(b * C + 0) * T + (size_t)c * L) * F + f;
    float* smooth = out + OFF_SMOOTH + ((size_t)b * T + (size_t)c * L) * F + f;

#pragma unroll
    for (int t = 0; t < L; ++t) {
        float2 v = inp[(size_t)t * F];           // L3-hot (carries read it last)
        float x = v.x * v.x + v.y * v.y;
        s = beta * s + a * x;
        float sm = sqrtf(s);
        float inv = 1.0f / (sm + 1e-8f);
        f32x2 rr;
        rr.x = v.x * inv * w0 + q0;
        rr.y = v.y * inv * w0 + q0;
        __builtin_nontemporal_store(rr, &res[(size_t)t * F]);
        __builtin_nontemporal_store(sm, &smooth[(size_t)t * F]);
    }
    if (c == NC - 1) out[OFF_SFINAL + (size_t)b * F + f] = s;  // pre-sqrt state
}

extern "C" void kernel_launch(void* const* d_in, const int* in_sizes, int n_in,
                              void* d_out, int out_size, void* d_ws, size_t ws_size,
                              hipStream_t stream) {
    const float* input       = (const float*)d_in[0];
    const float* s_1         = (const float*)d_in[1];
    const float* weights     = (const float*)d_in[2];
    const float* bias        = (const float*)d_in[3];
    const float* alpha_param = (const float*)d_in[4];
    float* out = (float*)d_out;

    float* carry = (float*)d_ws;   // B*NC*F floats = 1.64 MB

    k_phase1<<<G1 + G0, 256, 0, stream>>>(input, alpha_param, weights, bias, carry, out);
    k_phase2<<<G0, 256, 0, stream>>>(input, s_1, alpha_param, weights, bias, carry, out);
}